// Round 10
// baseline (651.869 us; speedup 1.0000x reference)
//
#include <hip/hip_runtime.h>
#include <math.h>

#define KNN 20
#define CNT_INV (1.0f / 1310720.0f)   // 1 / (B*N*K)

typedef short bf16x8 __attribute__((ext_vector_type(8)));   // 8 bf16 in 4 VGPRs
typedef float f32x4  __attribute__((ext_vector_type(4)));
typedef float f32x2  __attribute__((ext_vector_type(2)));   // VGPR pair -> v_pk_*_f32

__device__ __forceinline__ short f2bf(float f) {            // RNE f32->bf16
  unsigned u = __builtin_bit_cast(unsigned, f);
  u += 0x7FFFu + ((u >> 16) & 1u);
  return (short)(u >> 16);
}
__device__ __forceinline__ float lrelu(float y) { return y > 0.f ? y : 0.2f * y; }

// pack xt4[b][m] = {x, y, z, |x|^2}
__global__ __launch_bounds__(256) void xt4_kernel(const float* __restrict__ x,
                                                  float4* __restrict__ xt4) {
  const int t = blockIdx.x * 256 + threadIdx.x;   // < 65536
  const int b = t >> 12, m = t & 4095;
  const float* xb = x + (size_t)b * 12288;
  const float a = xb[m], c = xb[4096 + m], e = xb[8192 + m];
  xt4[t] = make_float4(a, c, e, a * a + c * c + e * e);
}

// ---------------------------------------------------------------------------
// KNN v11 (measured R7/R8: 237-240 us, VALUBusy ~65%, occupancy ~43%).
// Frozen: 3 rounds of micro-opts were neutral; remaining cost is pair-work
// + per-query fixed phases at this structure.
// ---------------------------------------------------------------------------
__global__ __launch_bounds__(256, 4) void knn_kernel(const float4* __restrict__ xt4,
                                                     int* __restrict__ idx_out,
                                                     const float* __restrict__ W1,
                                                     float* __restrict__ s1buf) {
  __shared__ __align__(16) int hist[1024];  // [query][256]
  __shared__ int sB[8];                     // {B,cnt} x4
  __shared__ int wcnt[4][4];
  __shared__ int slist[4][64];
  __shared__ int scnt[4];
  __shared__ int eidx[4][KNN];
  const int tid = threadIdx.x, lane = tid & 63, wid = tid >> 6;
  const int p0 = blockIdx.x * 4;
  const int b = p0 >> 12, n0 = p0 & 4095;
  const float4* xb4 = xt4 + (size_t)b * 4096;
  const float4 cp0 = xb4[n0], cp1 = xb4[n0 + 1], cp2 = xb4[n0 + 2], cp3 = xb4[n0 + 3];

  float w1r[6];
#pragma unroll
  for (int c = 0; c < 6; ++c) w1r[c] = W1[lane * 6 + c];

  // packed centers: lane0 = even query, lane1 = odd query
  const f32x2 cx01{cp0.x, cp1.x}, cy01{cp0.y, cp1.y}, cz01{cp0.z, cp1.z}, cw01{cp0.w, cp1.w};
  const f32x2 cx23{cp2.x, cp3.x}, cy23{cp2.y, cp3.y}, cz23{cp2.z, cp3.z}, cw23{cp2.w, cp3.w};
  const f32x2 m2{-2.0f, -2.0f};

  f32x2 d01[16], d23[16];
#pragma unroll
  for (int i = 0; i < 16; ++i) {
    const float4 qv = xb4[i * 256 + tid];   // ONE load, four queries
    const f32x2 qx{qv.x, qv.x}, qy{qv.y, qv.y}, qz{qv.z, qv.z}, qw{qv.w, qv.w};
    const f32x2 t01 = __builtin_elementwise_fma(cx01, qx,
                        __builtin_elementwise_fma(cy01, qy, cz01 * qz));
    const f32x2 t23 = __builtin_elementwise_fma(cx23, qx,
                        __builtin_elementwise_fma(cy23, qy, cz23 * qz));
    d01[i] = __builtin_elementwise_fma(m2, t01, qw) + cw01;  // ~-eps self -> bin 0
    d23[i] = __builtin_elementwise_fma(m2, t23, qw) + cw23;
  }

  // ---- PASS 1 (specialized): lo=0, R=2, bins = d2*128, upper guard only ----
  *(int4*)&hist[tid * 4] = int4{0, 0, 0, 0};
  __syncthreads();
#pragma unroll
  for (int i = 0; i < 16; ++i) {
    if (d01[i][0] < 2.0f) atomicAdd(&hist[      (int)(d01[i][0] * 128.0f)], 1);
    if (d01[i][1] < 2.0f) atomicAdd(&hist[256 + (int)(d01[i][1] * 128.0f)], 1);
    if (d23[i][0] < 2.0f) atomicAdd(&hist[512 + (int)(d23[i][0] * 128.0f)], 1);
    if (d23[i][1] < 2.0f) atomicAdd(&hist[768 + (int)(d23[i][1] * 128.0f)], 1);
  }
  __syncthreads();
  {   // wave w: chunk-progressive prefix scan of query w's histogram
    const int* h = &hist[wid * 256];
    int Bv = 256, cntv = 0, seam = 0;
#pragma unroll
    for (int c = 0; c < 4; ++c) {
      if (Bv == 256) {                     // wave-uniform early exit
        int s = h[c * 64 + lane];
#pragma unroll
        for (int off = 1; off < 64; off <<= 1) { const int t = __shfl_up(s, off); if (lane >= off) s += t; }
        s += seam;
        const unsigned long long m = __ballot(s >= 20);
        if (m) { const int l = __ffsll((long long)m) - 1; Bv = c * 64 + l; cntv = __shfl(s, l); }
        else seam = __shfl(s, 63);
      }
    }
    if (lane == 0) { sB[wid * 2] = Bv; sB[wid * 2 + 1] = cntv; }
  }
  __syncthreads();

  // ---- pass-1 block-uniform decisions ----
  float lo0 = 0.f, R0 = 2.f, lo1 = 0.f, R1 = 2.f, lo2 = 0.f, R2 = 2.f, lo3 = 0.f, R3 = 2.f;
  int bef0 = 0, bef1 = 0, bef2 = 0, bef3 = 0;
  float Dedge0 = 1e30f, Dedge1 = 1e30f, Dedge2 = 1e30f, Dedge3 = 1e30f;
  bool dn0 = false, dn1 = false, dn2 = false, dn3 = false;
  {
    const float bw = 2.0f * (1.0f / 256.0f);
    bool zm0 = false, zm1 = false, zm2 = false, zm3 = false;
    {
      const int Bq = sB[0], cq = sB[1];
      if (Bq == 256) R0 = 32.0f;
      else {
        Dedge0 = (float)(Bq + 1) * bw;
        if (cq <= 48) dn0 = true;
        else { lo0 = (float)Bq * bw; R0 = bw; zm0 = true; }
      }
    }
    {
      const int Bq = sB[2], cq = sB[3];
      if (Bq == 256) R1 = 32.0f;
      else {
        Dedge1 = (float)(Bq + 1) * bw;
        if (cq <= 48) dn1 = true;
        else { lo1 = (float)Bq * bw; R1 = bw; zm1 = true; }
      }
    }
    {
      const int Bq = sB[4], cq = sB[5];
      if (Bq == 256) R2 = 32.0f;
      else {
        Dedge2 = (float)(Bq + 1) * bw;
        if (cq <= 48) dn2 = true;
        else { lo2 = (float)Bq * bw; R2 = bw; zm2 = true; }
      }
    }
    {
      const int Bq = sB[6], cq = sB[7];
      if (Bq == 256) R3 = 32.0f;
      else {
        Dedge3 = (float)(Bq + 1) * bw;
        if (cq <= 48) dn3 = true;
        else { lo3 = (float)Bq * bw; R3 = bw; zm3 = true; }
      }
    }
    if (zm0) {
      int c = 0;
#pragma unroll
      for (int i = 0; i < 16; ++i) c += (int)__popcll(__ballot(d01[i][0] < lo0));
      if (lane == 0) wcnt[0][wid] = c;
    }
    if (zm1) {
      int c = 0;
#pragma unroll
      for (int i = 0; i < 16; ++i) c += (int)__popcll(__ballot(d01[i][1] < lo1));
      if (lane == 0) wcnt[1][wid] = c;
    }
    if (zm2) {
      int c = 0;
#pragma unroll
      for (int i = 0; i < 16; ++i) c += (int)__popcll(__ballot(d23[i][0] < lo2));
      if (lane == 0) wcnt[2][wid] = c;
    }
    if (zm3) {
      int c = 0;
#pragma unroll
      for (int i = 0; i < 16; ++i) c += (int)__popcll(__ballot(d23[i][1] < lo3));
      if (lane == 0) wcnt[3][wid] = c;
    }
    if (zm0 | zm1 | zm2 | zm3) {
      __syncthreads();
      if (zm0) bef0 = wcnt[0][0] + wcnt[0][1] + wcnt[0][2] + wcnt[0][3];
      if (zm1) bef1 = wcnt[1][0] + wcnt[1][1] + wcnt[1][2] + wcnt[1][3];
      if (zm2) bef2 = wcnt[2][0] + wcnt[2][1] + wcnt[2][2] + wcnt[2][3];
      if (zm3) bef3 = wcnt[3][0] + wcnt[3][1] + wcnt[3][2] + wcnt[3][3];
    }
  }

  // ---- adaptive fallback passes (rare) ----
  for (int pass = 1; pass < 6 && !(dn0 && dn1 && dn2 && dn3); ++pass) {
    *(int4*)&hist[tid * 4] = int4{0, 0, 0, 0};
    __syncthreads();
    const float sc0 = 256.0f / R0, sc1 = 256.0f / R1;
    const float sc2 = 256.0f / R2, sc3 = 256.0f / R3;
    if (!dn0) {
#pragma unroll
      for (int i = 0; i < 16; ++i) {
        const float rel = d01[i][0] - lo0;
        if (rel >= 0.0f && rel < R0) {
          int bin = (int)(rel * sc0); bin = bin > 255 ? 255 : bin;
          atomicAdd(&hist[bin], 1);
        }
      }
    }
    if (!dn1) {
#pragma unroll
      for (int i = 0; i < 16; ++i) {
        const float rel = d01[i][1] - lo1;
        if (rel >= 0.0f && rel < R1) {
          int bin = (int)(rel * sc1); bin = bin > 255 ? 255 : bin;
          atomicAdd(&hist[256 + bin], 1);
        }
      }
    }
    if (!dn2) {
#pragma unroll
      for (int i = 0; i < 16; ++i) {
        const float rel = d23[i][0] - lo2;
        if (rel >= 0.0f && rel < R2) {
          int bin = (int)(rel * sc2); bin = bin > 255 ? 255 : bin;
          atomicAdd(&hist[512 + bin], 1);
        }
      }
    }
    if (!dn3) {
#pragma unroll
      for (int i = 0; i < 16; ++i) {
        const float rel = d23[i][1] - lo3;
        if (rel >= 0.0f && rel < R3) {
          int bin = (int)(rel * sc3); bin = bin > 255 ? 255 : bin;
          atomicAdd(&hist[768 + bin], 1);
        }
      }
    }
    __syncthreads();
    {   // wave w: prefix scan of query w's histogram
      const bool skip = wid == 0 ? dn0 : wid == 1 ? dn1 : wid == 2 ? dn2 : dn3;
      if (!skip) {
        const int* h = &hist[wid * 256];
        int s0 = h[lane], s1 = h[64 + lane], s2 = h[128 + lane], s3 = h[192 + lane];
#pragma unroll
        for (int off = 1; off < 64; off <<= 1) { const int t = __shfl_up(s0, off); if (lane >= off) s0 += t; }
#pragma unroll
        for (int off = 1; off < 64; off <<= 1) { const int t = __shfl_up(s1, off); if (lane >= off) s1 += t; }
#pragma unroll
        for (int off = 1; off < 64; off <<= 1) { const int t = __shfl_up(s2, off); if (lane >= off) s2 += t; }
#pragma unroll
        for (int off = 1; off < 64; off <<= 1) { const int t = __shfl_up(s3, off); if (lane >= off) s3 += t; }
        s1 += __shfl(s0, 63);
        s2 += __shfl(s1, 63);
        s3 += __shfl(s2, 63);
        const int bef = wid == 0 ? bef0 : wid == 1 ? bef1 : wid == 2 ? bef2 : bef3;
        s0 += bef; s1 += bef; s2 += bef; s3 += bef;
        int B = 256, cnt = 0;
        unsigned long long m = __ballot(s0 >= 20);
        if (m) { const int l = __ffsll((long long)m) - 1; B = l; cnt = __shfl(s0, l); }
        else if ((m = __ballot(s1 >= 20)) != 0ull) { const int l = __ffsll((long long)m) - 1; B = 64 + l; cnt = __shfl(s1, l); }
        else if ((m = __ballot(s2 >= 20)) != 0ull) { const int l = __ffsll((long long)m) - 1; B = 128 + l; cnt = __shfl(s2, l); }
        else if ((m = __ballot(s3 >= 20)) != 0ull) { const int l = __ffsll((long long)m) - 1; B = 192 + l; cnt = __shfl(s3, l); }
        if (lane == 0) { sB[wid * 2] = B; sB[wid * 2 + 1] = cnt; }
      }
    }
    __syncthreads();
    // block-uniform per-query decisions
    bool zm0 = false, zm1 = false, zm2 = false, zm3 = false;
    if (!dn0) {
      const int Bq = sB[0], cq = sB[1];
      if (Bq == 256) R0 *= 16.0f;
      else {
        const float bw = R0 * (1.0f / 256.0f);
        Dedge0 = lo0 + (float)(Bq + 1) * bw;
        if (cq <= 48) dn0 = true;
        else { lo0 += (float)Bq * bw; R0 = bw; zm0 = true; }
      }
    }
    if (!dn1) {
      const int Bq = sB[2], cq = sB[3];
      if (Bq == 256) R1 *= 16.0f;
      else {
        const float bw = R1 * (1.0f / 256.0f);
        Dedge1 = lo1 + (float)(Bq + 1) * bw;
        if (cq <= 48) dn1 = true;
        else { lo1 += (float)Bq * bw; R1 = bw; zm1 = true; }
      }
    }
    if (!dn2) {
      const int Bq = sB[4], cq = sB[5];
      if (Bq == 256) R2 *= 16.0f;
      else {
        const float bw = R2 * (1.0f / 256.0f);
        Dedge2 = lo2 + (float)(Bq + 1) * bw;
        if (cq <= 48) dn2 = true;
        else { lo2 += (float)Bq * bw; R2 = bw; zm2 = true; }
      }
    }
    if (!dn3) {
      const int Bq = sB[6], cq = sB[7];
      if (Bq == 256) R3 *= 16.0f;
      else {
        const float bw = R3 * (1.0f / 256.0f);
        Dedge3 = lo3 + (float)(Bq + 1) * bw;
        if (cq <= 48) dn3 = true;
        else { lo3 += (float)Bq * bw; R3 = bw; zm3 = true; }
      }
    }
    if (zm0) {
      int c = 0;
#pragma unroll
      for (int i = 0; i < 16; ++i) c += (int)__popcll(__ballot(d01[i][0] < lo0));
      if (lane == 0) wcnt[0][wid] = c;
    }
    if (zm1) {
      int c = 0;
#pragma unroll
      for (int i = 0; i < 16; ++i) c += (int)__popcll(__ballot(d01[i][1] < lo1));
      if (lane == 0) wcnt[1][wid] = c;
    }
    if (zm2) {
      int c = 0;
#pragma unroll
      for (int i = 0; i < 16; ++i) c += (int)__popcll(__ballot(d23[i][0] < lo2));
      if (lane == 0) wcnt[2][wid] = c;
    }
    if (zm3) {
      int c = 0;
#pragma unroll
      for (int i = 0; i < 16; ++i) c += (int)__popcll(__ballot(d23[i][1] < lo3));
      if (lane == 0) wcnt[3][wid] = c;
    }
    if (zm0 | zm1 | zm2 | zm3) {
      __syncthreads();
      if (zm0) bef0 = wcnt[0][0] + wcnt[0][1] + wcnt[0][2] + wcnt[0][3];
      if (zm1) bef1 = wcnt[1][0] + wcnt[1][1] + wcnt[1][2] + wcnt[1][3];
      if (zm2) bef2 = wcnt[2][0] + wcnt[2][1] + wcnt[2][2] + wcnt[2][3];
      if (zm3) bef3 = wcnt[3][0] + wcnt[3][1] + wcnt[3][2] + wcnt[3][3];
    }
  }

  // ---- margin collect (all four queries) ----
  if (tid < 4) scnt[tid] = 0;
  __syncthreads();
  const float T0 = Dedge0 + 4e-3f, T1 = Dedge1 + 4e-3f;
  const float T2 = Dedge2 + 4e-3f, T3 = Dedge3 + 4e-3f;
#pragma unroll
  for (int i = 0; i < 16; ++i) {
    if (d01[i][0] < T0) {
      const int pos = atomicAdd(&scnt[0], 1);
      if (pos < 64) slist[0][pos] = i * 256 + tid;
    }
    if (d01[i][1] < T1) {
      const int pos = atomicAdd(&scnt[1], 1);
      if (pos < 64) slist[1][pos] = i * 256 + tid;
    }
    if (d23[i][0] < T2) {
      const int pos = atomicAdd(&scnt[2], 1);
      if (pos < 64) slist[2][pos] = i * 256 + tid;
    }
    if (d23[i][1] < T3) {
      const int pos = atomicAdd(&scnt[3], 1);
      if (pos < 64) slist[3][pos] = i * 256 + tid;
    }
  }
  __syncthreads();

  // wave w: f64 re-rank of query w (reference op order -> exact top-20 set)
  const float4 cp = wid == 0 ? cp0 : wid == 1 ? cp1 : wid == 2 ? cp2 : cp3;
  {
    const int s = min(scnt[wid], 64);
    int myi = -1; double myd = -1.0e300;
    if (lane < s) {
      myi = slist[wid][lane];
      const float4 av = xb4[myi];
      const double c0 = (double)cp.x, c1 = (double)cp.y, c2 = (double)cp.z;
      const double a0 = (double)av.x, a1 = (double)av.y, a2 = (double)av.z;
      const double dot = c0 * a0 + c1 * a1 + c2 * a2;
      const double sqm = a0 * a0 + a1 * a1 + a2 * a2;
      const double sn  = c0 * c0 + c1 * c1 + c2 * c2;
      myd = (2.0 * dot - sn) - sqm;
    }
    int rank = 0;
    for (int j = 0; j < s; ++j) {
      const double od = __shfl(myd, j);
      const int    oi = __shfl(myi, j);
      if (od > myd || (od == myd && oi < myi)) ++rank;
    }
    if (lane < s && rank < KNN) {
      idx_out[(p0 + wid) * KNN + rank] = myi;
      eidx[wid][rank] = myi;
    }
  }
  // same-wave LDS write->read is in-order; no barrier needed before stats.

  // fused layer-1 stats: wave w handles query w, all 20 k, ch = lane
  const float base1 = (w1r[3] - w1r[0]) * cp.x + (w1r[4] - w1r[1]) * cp.y +
                      (w1r[5] - w1r[2]) * cp.z;
  float sm = 0.f, sq = 0.f;
#pragma unroll
  for (int t = 0; t < KNN; ++t) {
    const int kk = eidx[wid][t];
    const float4 qv = xb4[kk];                // same-addr broadcast
    float y = fmaf(w1r[0], qv.x, fmaf(w1r[1], qv.y, fmaf(w1r[2], qv.z, base1)));
    y = lrelu(y);
    sm += y; sq = fmaf(y, y, sq);
  }
  float* bk = s1buf + (size_t)((p0 + wid) & 255) * 128;
  atomicAdd(&bk[lane], sm);
  atomicAdd(&bk[64 + lane], sq);
}

// ---------------------------------------------------------------------------
// Stage kernel (MFMA): one wave per point, 4 waves/block, 8 points/wave.
// Gather pipelined (idx 2 ahead, gather 1 ahead). MINW: stage2=3, stage3=2
// (R8 measured: stage3 MINW=3 regressed +7us — reverted; (256,4) breaks).
// ---------------------------------------------------------------------------
template <int STAGE, int MINW>
__global__ __launch_bounds__(256, MINW) void stage_kernel(
    const float4* __restrict__ xt4, const int* __restrict__ nbr,
    const float* __restrict__ W1,
    const float* __restrict__ w2ft, const float* __restrict__ b2f,
    const float* __restrict__ w3ft, const float* __restrict__ b3f,
    float* __restrict__ sumO, float* __restrict__ sqO,
    float* __restrict__ mx, float* __restrict__ mn) {
  __shared__ float pts[4][96];          // float4 per k, center at 80..83
  __shared__ float W1T[384];
  __shared__ short abuf[4][2048];       // per-wave A-frag buffer
  __shared__ float redS[256], redQ[256];

  const int tid = threadIdx.x, wave = tid >> 6, lane = tid & 63;
  const int q = lane >> 4, cc = lane & 15;

  for (int i = tid; i < 384; i += 256) W1T[i] = W1[(i & 63) * 6 + (i >> 6)];
  __syncthreads();

  float w1r[6];
#pragma unroll
  for (int c = 0; c < 6; ++c) w1r[c] = W1T[c * 64 + lane];

  bf16x8 w2f[2][4];
#pragma unroll
  for (int kt = 0; kt < 2; ++kt)
#pragma unroll
    for (int nt = 0; nt < 4; ++nt)
#pragma unroll
      for (int j = 0; j < 8; ++j)
        w2f[kt][nt][j] = f2bf(w2ft[(kt * 32 + q * 8 + j) * 64 + nt * 16 + cc]);
  float bias2v[4];
#pragma unroll
  for (int nt = 0; nt < 4; ++nt) bias2v[nt] = b2f[nt * 16 + cc];

  bf16x8 w3f[2][4];
  float bias3v[4];
  if (STAGE == 3) {
#pragma unroll
    for (int kt = 0; kt < 2; ++kt)
#pragma unroll
      for (int nt = 0; nt < 4; ++nt)
#pragma unroll
        for (int j = 0; j < 8; ++j)
          w3f[kt][nt][j] = f2bf(w3ft[(kt * 32 + q * 8 + j) * 64 + nt * 16 + cc]);
#pragma unroll
    for (int nt = 0; nt < 4; ++nt) bias3v[nt] = b3f[nt * 16 + cc];
  }

  const int kt1 = lane >> 5, q1 = (lane & 31) >> 3, j1 = lane & 7;
  short* ab = abuf[wave];
  const bf16x8* ab8 = (const bf16x8*)ab;
  float* pw = pts[wave];

  float s_s[4] = {0.f, 0.f, 0.f, 0.f}, s_q[4] = {0.f, 0.f, 0.f, 0.f};
  const int wgid = blockIdx.x * 4 + wave;

  // --- pipelined gather state ---
  const int stepN = 8192 * KNN;
  const int* nbp = nbr + (size_t)wgid * KNN + lane;      // valid for lane<KNN
  const float4* xb0 = xt4 + (size_t)(wgid >> 12) * 4096; // batch base, it=0
  const int nn = wgid & 4095;                            // it-invariant
  int kkB = 0;
  float4 g;
  if (lane < KNN) {
    const int kkA = nbp[0];
    g = xb0[kkA];
    kkB = nbp[stepN];                                    // idx for it=1
  } else if (lane == KNN) {
    g = xb0[nn];
  }
  const int* nbp2 = nbp + 2 * stepN;                     // idx ptr for it+2
  const float4* xbn = xb0 + 8192;                        // batch base, it+1

  for (int it = 0; it < 8; ++it) {
    const int p = wgid + it * 8192;
    if (lane <= KNN) *(float4*)&pw[lane * 4] = g;
    // prefetch next point's gather (kkB ready) and idx two ahead
    float4 gn = g; int kkC = kkB;
    if (it < 7 && lane <= KNN) gn = (lane < KNN) ? xbn[kkB] : xbn[nn];
    if (it < 6 && lane < KNN) kkC = nbp2[0];

    const float cx0 = pw[80], cx1 = pw[81], cx2 = pw[82];
    const float base1 = (w1r[3] - w1r[0]) * cx0 + (w1r[4] - w1r[1]) * cx1 +
                        (w1r[5] - w1r[2]) * cx2;

#pragma unroll
    for (int k = 0; k < KNN; ++k) {
      const float4 pk = *(const float4*)&pw[k * 4];
      float y = fmaf(w1r[0], pk.x, fmaf(w1r[1], pk.y, fmaf(w1r[2], pk.z, base1)));
      y = lrelu(y);
      ab[(((k >> 4) * 2 + kt1) * 64 + q1 * 16 + (k & 15)) * 8 + j1] = f2bf(y);
    }

    f32x4 acc2[2][4];
#pragma unroll
    for (int mt = 0; mt < 2; ++mt)
#pragma unroll
      for (int nt = 0; nt < 4; ++nt)
        acc2[mt][nt] = f32x4{bias2v[nt], bias2v[nt], bias2v[nt], bias2v[nt]};
#pragma unroll
    for (int kt = 0; kt < 2; ++kt) {
      const bf16x8 a0 = ab8[(0 * 2 + kt) * 64 + lane];
      const bf16x8 a1 = ab8[(1 * 2 + kt) * 64 + lane];
#pragma unroll
      for (int nt = 0; nt < 4; ++nt) {
        acc2[0][nt] = __builtin_amdgcn_mfma_f32_16x16x32_bf16(a0, w2f[kt][nt], acc2[0][nt], 0, 0, 0);
        acc2[1][nt] = __builtin_amdgcn_mfma_f32_16x16x32_bf16(a1, w2f[kt][nt], acc2[1][nt], 0, 0, 0);
      }
    }

    if (STAGE == 2) {
#pragma unroll
      for (int mt = 0; mt < 2; ++mt)
#pragma unroll
        for (int nt = 0; nt < 4; ++nt)
#pragma unroll
          for (int r = 0; r < 4; ++r) {
            if (mt == 1 && q != 0) continue;
            const float y = lrelu(acc2[mt][nt][r]);
            s_s[nt] += y; s_q[nt] += y * y;
          }
    } else {
#pragma unroll
      for (int mt = 0; mt < 2; ++mt)
#pragma unroll
        for (int nt = 0; nt < 4; ++nt) {
          const int kt3 = nt >> 1;
          const int q3 = (nt & 1) * 2 + (cc >> 3);
          const int j3 = cc & 7;
#pragma unroll
          for (int r = 0; r < 4; ++r) {
            if (mt == 1 && q != 0) continue;
            const float y = lrelu(acc2[mt][nt][r]);
            ab[((mt * 2 + kt3) * 64 + q3 * 16 + q * 4 + r) * 8 + j3] = f2bf(y);
          }
        }

      f32x4 acc3[2][4];
#pragma unroll
      for (int mt = 0; mt < 2; ++mt)
#pragma unroll
        for (int nt = 0; nt < 4; ++nt)
          acc3[mt][nt] = f32x4{bias3v[nt], bias3v[nt], bias3v[nt], bias3v[nt]};
#pragma unroll
      for (int kt = 0; kt < 2; ++kt) {
        const bf16x8 a0 = ab8[(0 * 2 + kt) * 64 + lane];
        const bf16x8 a1 = ab8[(1 * 2 + kt) * 64 + lane];
#pragma unroll
        for (int nt = 0; nt < 4; ++nt) {
          acc3[0][nt] = __builtin_amdgcn_mfma_f32_16x16x32_bf16(a0, w3f[kt][nt], acc3[0][nt], 0, 0, 0);
          acc3[1][nt] = __builtin_amdgcn_mfma_f32_16x16x32_bf16(a1, w3f[kt][nt], acc3[1][nt], 0, 0, 0);
        }
      }

      float vmx[4], vmn[4];
#pragma unroll
      for (int nt = 0; nt < 4; ++nt) { vmx[nt] = -INFINITY; vmn[nt] = INFINITY; }
#pragma unroll
      for (int mt = 0; mt < 2; ++mt)
#pragma unroll
        for (int nt = 0; nt < 4; ++nt)
#pragma unroll
          for (int r = 0; r < 4; ++r) {
            if (mt == 1 && q != 0) continue;
            const float y = lrelu(acc3[mt][nt][r]);
            s_s[nt] += y; s_q[nt] += y * y;
            vmx[nt] = fmaxf(vmx[nt], y); vmn[nt] = fminf(vmn[nt], y);
          }
#pragma unroll
      for (int nt = 0; nt < 4; ++nt) {
        vmx[nt] = fmaxf(vmx[nt], __shfl_xor(vmx[nt], 16));
        vmx[nt] = fmaxf(vmx[nt], __shfl_xor(vmx[nt], 32));
        vmn[nt] = fminf(vmn[nt], __shfl_xor(vmn[nt], 16));
        vmn[nt] = fminf(vmn[nt], __shfl_xor(vmn[nt], 32));
      }
      const float omx = q == 0 ? vmx[0] : q == 1 ? vmx[1] : q == 2 ? vmx[2] : vmx[3];
      const float omn = q == 0 ? vmn[0] : q == 1 ? vmn[1] : q == 2 ? vmn[2] : vmn[3];
      mx[(size_t)p * 64 + lane] = omx;
      mn[(size_t)p * 64 + lane] = omn;
    }

    g = gn; kkB = kkC; nbp2 += stepN; xbn += 8192;
  }

#pragma unroll
  for (int nt = 0; nt < 4; ++nt) {
    s_s[nt] += __shfl_xor(s_s[nt], 16); s_s[nt] += __shfl_xor(s_s[nt], 32);
    s_q[nt] += __shfl_xor(s_q[nt], 16); s_q[nt] += __shfl_xor(s_q[nt], 32);
  }
  const float ms = q == 0 ? s_s[0] : q == 1 ? s_s[1] : q == 2 ? s_s[2] : s_s[3];
  const float mq = q == 0 ? s_q[0] : q == 1 ? s_q[1] : q == 2 ? s_q[2] : s_q[3];
  redS[tid] = ms; redQ[tid] = mq;
  __syncthreads();
  if (tid < 64) {
    const float s  = redS[tid] + redS[64 + tid] + redS[128 + tid] + redS[192 + tid];
    const float qq = redQ[tid] + redQ[64 + tid] + redQ[128 + tid] + redQ[192 + tid];
    atomicAdd(&sumO[tid], s);
    atomicAdd(&sqO[tid], qq);
  }
}

// fold1 v2 (R6): 256 threads — thread (o=tid&63, qt=tid>>6) sums bucket
// quarter qt, LDS-reduce, then quarter-split W-fold. Same math, 4x parallel.
__global__ __launch_bounds__(256) void fold1_kernel(
    const float* __restrict__ s1buf,
    const float* __restrict__ g, const float* __restrict__ bt,
    const float* __restrict__ W,
    float* __restrict__ WfT, float* __restrict__ bf) {
  __shared__ float rs[256], rq[256];
  __shared__ float s[64], t[64];
  const int tid = threadIdx.x, o = tid & 63, qt = tid >> 6;
  float sm = 0.f, qq = 0.f;
  for (int k = qt; k < 256; k += 4) {
    sm += s1buf[k * 128 + o];
    qq += s1buf[k * 128 + 64 + o];
  }
  rs[tid] = sm; rq[tid] = qq;
  __syncthreads();
  if (tid < 64) {
    sm = rs[o] + rs[64 + o] + rs[128 + o] + rs[192 + o];
    qq = rq[o] + rq[64 + o] + rq[128 + o] + rq[192 + o];
    const float mu = sm * CNT_INV;
    const float var = qq * CNT_INV - mu * mu;
    const float sc = g[o] / sqrtf(var + 1e-5f);
    s[o] = sc; t[o] = bt[o] - mu * sc;
  }
  __syncthreads();
  float acc = 0.f;
  for (int c = qt * 16; c < qt * 16 + 16; ++c) {
    const float w = W[o * 64 + c];
    WfT[c * 64 + o] = w * s[c];
    acc = fmaf(w, t[c], acc);
  }
  rs[tid] = acc;
  __syncthreads();
  if (tid < 64) bf[o] = rs[o] + rs[64 + o] + rs[128 + o] + rs[192 + o];
}

__global__ void fold_kernel(const float* __restrict__ sum, const float* __restrict__ sq,
                            const float* __restrict__ g, const float* __restrict__ bt,
                            const float* __restrict__ W,
                            float* __restrict__ WfT, float* __restrict__ bf) {
  __shared__ float s[64], t[64];
  const int o = threadIdx.x;
  const float mu = sum[o] * CNT_INV;
  const float var = sq[o] * CNT_INV - mu * mu;
  const float sc = g[o] / sqrtf(var + 1e-5f);
  s[o] = sc; t[o] = bt[o] - mu * sc;
  __syncthreads();
  float acc = 0.f;
  for (int c = 0; c < 64; ++c) {
    const float w = W[o * 64 + c];
    WfT[c * 64 + o] = w * s[c];
    acc += w * t[c];
  }
  bf[o] = acc;
}

// final (R6): fold3 fused — each block derives s3/t3 from BN3 raw stats.
// 64x64 LDS transpose tile; coalesced reads of mx/mn AND writes of out.
// out[b][o][n] = s3[o] * (s3>=0 ? max_k : min_k) + t3[o]
__global__ __launch_bounds__(256) void final_kernel(
    const float* __restrict__ mx, const float* __restrict__ mn,
    const float* __restrict__ sum3, const float* __restrict__ sq3,
    const float* __restrict__ g2, const float* __restrict__ b2,
    float* __restrict__ out) {
  __shared__ float tmx[64][65], tmn[64][65];
  __shared__ float ss[64], tt[64];
  const int tid = threadIdx.x;
  const int P = blockIdx.x * 64;              // 64 points, same batch b
  const int b = P >> 12, nb = P & 4095;
  if (tid < 64) {
    const float mu = sum3[tid] * CNT_INV;
    const float var = sq3[tid] * CNT_INV - mu * mu;
    const float sc = g2[tid] / sqrtf(var + 1e-5f);
    ss[tid] = sc; tt[tid] = b2[tid] - mu * sc;
  }
#pragma unroll
  for (int r = 0; r < 16; ++r) {
    const int idx = r * 256 + tid;            // point-local row, channel
    const int pl = idx >> 6, ch = idx & 63;
    const size_t src = ((size_t)(P + pl)) * 64 + ch;
    tmx[pl][ch] = mx[src];
    tmn[pl][ch] = mn[src];
  }
  __syncthreads();
  const int nl = tid & 63;
#pragma unroll
  for (int r = 0; r < 16; ++r) {
    const int o = (tid >> 6) + r * 4;
    const float sc = ss[o];
    const float v = sc >= 0.f ? tmx[nl][o] : tmn[nl][o];
    out[(size_t)b * 262144 + (size_t)o * 4096 + nb + nl] = sc * v + tt[o];
  }
}

extern "C" void kernel_launch(void* const* d_in, const int* in_sizes, int n_in,
                              void* d_out, int out_size, void* d_ws, size_t ws_size,
                              hipStream_t stream) {
  const float* x  = (const float*)d_in[0];
  const float* W1 = (const float*)d_in[1];
  const float* W2 = (const float*)d_in[2];
  const float* W3 = (const float*)d_in[3];
  const float* g1 = (const float*)d_in[4];
  const float* b1 = (const float*)d_in[5];
  const float* g2 = (const float*)d_in[6];
  const float* b2 = (const float*)d_in[7];
  float* out = (float*)d_out;

  char* ws = (char*)d_ws;
  float4* xt4 = (float4*)ws;                        // 1,048,576 B
  int* idx = (int*)(ws + 1048576);                  // 5,242,880 B
  float* F = (float*)(ws + 6291456);
  float* sum2 = F + 0,   * sq2 = F + 64;
  float* sum3 = F + 128, * sq3 = F + 192;
  float* s1buf = F + 256;                           // 256 buckets x 128
  float* W2fT = F + 33024;
  float* b2f  = F + 37120;
  float* W3fT = F + 37184;
  float* b3f  = F + 41280;
  float* sum3d = F + 41344;                         // dummy stats for dup run
  float* sq3d  = F + 41408;                         // (never read)
  float* mx = (float*)(ws + 6457344);               // [B*N][64]
  float* mn = mx + (size_t)16 * 4096 * 64;          // ends at 40,011,776

  // R9 MEASUREMENT: duplicate stage3 into scratch — wall-time delta vs the
  // ~520us baseline reveals stage3's true duration (never visible in top-5).
  const size_t MX2_OFF  = 40013824;                 // 4KB aligned
  const size_t MX2_SIZE = (size_t)16 * 4096 * 64 * 4 * 2;   // mx2+mn2 = 32MB
  float* mx2 = (float*)(ws + MX2_OFF);
  float* mn2 = mx2 + (size_t)16 * 4096 * 64;
  const bool dup_ok = ws_size >= MX2_OFF + MX2_SIZE;

  hipMemsetAsync(F, 0, 33024 * sizeof(float), stream);   // stats + buckets

  xt4_kernel<<<256, 256, 0, stream>>>(x, xt4);
  knn_kernel<<<16384, 256, 0, stream>>>(xt4, idx, W1, s1buf);
  fold1_kernel<<<1, 256, 0, stream>>>(s1buf, g1, b1, W2, W2fT, b2f);
  stage_kernel<2, 3><<<2048, 256, 0, stream>>>(xt4, idx, W1, W2fT, b2f, nullptr,
                                               nullptr, sum2, sq2, nullptr, nullptr);
  fold_kernel<<<1, 64, 0, stream>>>(sum2, sq2, g1, b1, W3, W3fT, b3f);
  stage_kernel<3, 2><<<2048, 256, 0, stream>>>(xt4, idx, W1, W2fT, b2f, W3fT,
                                               b3f, sum3, sq3, mx, mn);
  if (dup_ok) {   // timing probe only: outputs go to scratch, never read
    stage_kernel<3, 2><<<2048, 256, 0, stream>>>(xt4, idx, W1, W2fT, b2f, W3fT,
                                                 b3f, sum3d, sq3d, mx2, mn2);
  }
  final_kernel<<<1024, 256, 0, stream>>>(mx, mn, sum3, sq3, g2, b2, out);
}

// Round 11
// 505.797 us; speedup vs baseline: 1.2888x; 1.2888x over previous
//
#include <hip/hip_runtime.h>
#include <math.h>

#define KNN 20
#define CNT_INV (1.0f / 1310720.0f)   // 1 / (B*N*K)

typedef short bf16x8 __attribute__((ext_vector_type(8)));   // 8 bf16 in 4 VGPRs
typedef float f32x4  __attribute__((ext_vector_type(4)));
typedef float f32x2  __attribute__((ext_vector_type(2)));   // VGPR pair -> v_pk_*_f32

__device__ __forceinline__ short f2bf(float f) {            // RNE f32->bf16
  unsigned u = __builtin_bit_cast(unsigned, f);
  u += 0x7FFFu + ((u >> 16) & 1u);
  return (short)(u >> 16);
}
__device__ __forceinline__ float lrelu(float y) { return y > 0.f ? y : 0.2f * y; }

// pack xt4[b][m] = {x, y, z, |x|^2}
__global__ __launch_bounds__(256) void xt4_kernel(const float* __restrict__ x,
                                                  float4* __restrict__ xt4) {
  const int t = blockIdx.x * 256 + threadIdx.x;   // < 65536
  const int b = t >> 12, m = t & 4095;
  const float* xb = x + (size_t)b * 12288;
  const float a = xb[m], c = xb[4096 + m], e = xb[8192 + m];
  xt4[t] = make_float4(a, c, e, a * a + c * c + e * e);
}

// ---------------------------------------------------------------------------
// KNN v11 (measured R7-R10: 237-240 us, VALUBusy ~65%, occupancy ~43%).
// Frozen: micro-opts were neutral; remaining cost is pair-work + per-query
// fixed phases at this structure.
// ---------------------------------------------------------------------------
__global__ __launch_bounds__(256, 4) void knn_kernel(const float4* __restrict__ xt4,
                                                     int* __restrict__ idx_out,
                                                     const float* __restrict__ W1,
                                                     float* __restrict__ s1buf) {
  __shared__ __align__(16) int hist[1024];  // [query][256]
  __shared__ int sB[8];                     // {B,cnt} x4
  __shared__ int wcnt[4][4];
  __shared__ int slist[4][64];
  __shared__ int scnt[4];
  __shared__ int eidx[4][KNN];
  const int tid = threadIdx.x, lane = tid & 63, wid = tid >> 6;
  const int p0 = blockIdx.x * 4;
  const int b = p0 >> 12, n0 = p0 & 4095;
  const float4* xb4 = xt4 + (size_t)b * 4096;
  const float4 cp0 = xb4[n0], cp1 = xb4[n0 + 1], cp2 = xb4[n0 + 2], cp3 = xb4[n0 + 3];

  float w1r[6];
#pragma unroll
  for (int c = 0; c < 6; ++c) w1r[c] = W1[lane * 6 + c];

  // packed centers: lane0 = even query, lane1 = odd query
  const f32x2 cx01{cp0.x, cp1.x}, cy01{cp0.y, cp1.y}, cz01{cp0.z, cp1.z}, cw01{cp0.w, cp1.w};
  const f32x2 cx23{cp2.x, cp3.x}, cy23{cp2.y, cp3.y}, cz23{cp2.z, cp3.z}, cw23{cp2.w, cp3.w};
  const f32x2 m2{-2.0f, -2.0f};

  f32x2 d01[16], d23[16];
#pragma unroll
  for (int i = 0; i < 16; ++i) {
    const float4 qv = xb4[i * 256 + tid];   // ONE load, four queries
    const f32x2 qx{qv.x, qv.x}, qy{qv.y, qv.y}, qz{qv.z, qv.z}, qw{qv.w, qv.w};
    const f32x2 t01 = __builtin_elementwise_fma(cx01, qx,
                        __builtin_elementwise_fma(cy01, qy, cz01 * qz));
    const f32x2 t23 = __builtin_elementwise_fma(cx23, qx,
                        __builtin_elementwise_fma(cy23, qy, cz23 * qz));
    d01[i] = __builtin_elementwise_fma(m2, t01, qw) + cw01;  // ~-eps self -> bin 0
    d23[i] = __builtin_elementwise_fma(m2, t23, qw) + cw23;
  }

  // ---- PASS 1 (specialized): lo=0, R=2, bins = d2*128, upper guard only ----
  *(int4*)&hist[tid * 4] = int4{0, 0, 0, 0};
  __syncthreads();
#pragma unroll
  for (int i = 0; i < 16; ++i) {
    if (d01[i][0] < 2.0f) atomicAdd(&hist[      (int)(d01[i][0] * 128.0f)], 1);
    if (d01[i][1] < 2.0f) atomicAdd(&hist[256 + (int)(d01[i][1] * 128.0f)], 1);
    if (d23[i][0] < 2.0f) atomicAdd(&hist[512 + (int)(d23[i][0] * 128.0f)], 1);
    if (d23[i][1] < 2.0f) atomicAdd(&hist[768 + (int)(d23[i][1] * 128.0f)], 1);
  }
  __syncthreads();
  {   // wave w: chunk-progressive prefix scan of query w's histogram
    const int* h = &hist[wid * 256];
    int Bv = 256, cntv = 0, seam = 0;
#pragma unroll
    for (int c = 0; c < 4; ++c) {
      if (Bv == 256) {                     // wave-uniform early exit
        int s = h[c * 64 + lane];
#pragma unroll
        for (int off = 1; off < 64; off <<= 1) { const int t = __shfl_up(s, off); if (lane >= off) s += t; }
        s += seam;
        const unsigned long long m = __ballot(s >= 20);
        if (m) { const int l = __ffsll((long long)m) - 1; Bv = c * 64 + l; cntv = __shfl(s, l); }
        else seam = __shfl(s, 63);
      }
    }
    if (lane == 0) { sB[wid * 2] = Bv; sB[wid * 2 + 1] = cntv; }
  }
  __syncthreads();

  // ---- pass-1 block-uniform decisions ----
  float lo0 = 0.f, R0 = 2.f, lo1 = 0.f, R1 = 2.f, lo2 = 0.f, R2 = 2.f, lo3 = 0.f, R3 = 2.f;
  int bef0 = 0, bef1 = 0, bef2 = 0, bef3 = 0;
  float Dedge0 = 1e30f, Dedge1 = 1e30f, Dedge2 = 1e30f, Dedge3 = 1e30f;
  bool dn0 = false, dn1 = false, dn2 = false, dn3 = false;
  {
    const float bw = 2.0f * (1.0f / 256.0f);
    bool zm0 = false, zm1 = false, zm2 = false, zm3 = false;
    {
      const int Bq = sB[0], cq = sB[1];
      if (Bq == 256) R0 = 32.0f;
      else {
        Dedge0 = (float)(Bq + 1) * bw;
        if (cq <= 48) dn0 = true;
        else { lo0 = (float)Bq * bw; R0 = bw; zm0 = true; }
      }
    }
    {
      const int Bq = sB[2], cq = sB[3];
      if (Bq == 256) R1 = 32.0f;
      else {
        Dedge1 = (float)(Bq + 1) * bw;
        if (cq <= 48) dn1 = true;
        else { lo1 = (float)Bq * bw; R1 = bw; zm1 = true; }
      }
    }
    {
      const int Bq = sB[4], cq = sB[5];
      if (Bq == 256) R2 = 32.0f;
      else {
        Dedge2 = (float)(Bq + 1) * bw;
        if (cq <= 48) dn2 = true;
        else { lo2 = (float)Bq * bw; R2 = bw; zm2 = true; }
      }
    }
    {
      const int Bq = sB[6], cq = sB[7];
      if (Bq == 256) R3 = 32.0f;
      else {
        Dedge3 = (float)(Bq + 1) * bw;
        if (cq <= 48) dn3 = true;
        else { lo3 = (float)Bq * bw; R3 = bw; zm3 = true; }
      }
    }
    if (zm0) {
      int c = 0;
#pragma unroll
      for (int i = 0; i < 16; ++i) c += (int)__popcll(__ballot(d01[i][0] < lo0));
      if (lane == 0) wcnt[0][wid] = c;
    }
    if (zm1) {
      int c = 0;
#pragma unroll
      for (int i = 0; i < 16; ++i) c += (int)__popcll(__ballot(d01[i][1] < lo1));
      if (lane == 0) wcnt[1][wid] = c;
    }
    if (zm2) {
      int c = 0;
#pragma unroll
      for (int i = 0; i < 16; ++i) c += (int)__popcll(__ballot(d23[i][0] < lo2));
      if (lane == 0) wcnt[2][wid] = c;
    }
    if (zm3) {
      int c = 0;
#pragma unroll
      for (int i = 0; i < 16; ++i) c += (int)__popcll(__ballot(d23[i][1] < lo3));
      if (lane == 0) wcnt[3][wid] = c;
    }
    if (zm0 | zm1 | zm2 | zm3) {
      __syncthreads();
      if (zm0) bef0 = wcnt[0][0] + wcnt[0][1] + wcnt[0][2] + wcnt[0][3];
      if (zm1) bef1 = wcnt[1][0] + wcnt[1][1] + wcnt[1][2] + wcnt[1][3];
      if (zm2) bef2 = wcnt[2][0] + wcnt[2][1] + wcnt[2][2] + wcnt[2][3];
      if (zm3) bef3 = wcnt[3][0] + wcnt[3][1] + wcnt[3][2] + wcnt[3][3];
    }
  }

  // ---- adaptive fallback passes (rare) ----
  for (int pass = 1; pass < 6 && !(dn0 && dn1 && dn2 && dn3); ++pass) {
    *(int4*)&hist[tid * 4] = int4{0, 0, 0, 0};
    __syncthreads();
    const float sc0 = 256.0f / R0, sc1 = 256.0f / R1;
    const float sc2 = 256.0f / R2, sc3 = 256.0f / R3;
    if (!dn0) {
#pragma unroll
      for (int i = 0; i < 16; ++i) {
        const float rel = d01[i][0] - lo0;
        if (rel >= 0.0f && rel < R0) {
          int bin = (int)(rel * sc0); bin = bin > 255 ? 255 : bin;
          atomicAdd(&hist[bin], 1);
        }
      }
    }
    if (!dn1) {
#pragma unroll
      for (int i = 0; i < 16; ++i) {
        const float rel = d01[i][1] - lo1;
        if (rel >= 0.0f && rel < R1) {
          int bin = (int)(rel * sc1); bin = bin > 255 ? 255 : bin;
          atomicAdd(&hist[256 + bin], 1);
        }
      }
    }
    if (!dn2) {
#pragma unroll
      for (int i = 0; i < 16; ++i) {
        const float rel = d23[i][0] - lo2;
        if (rel >= 0.0f && rel < R2) {
          int bin = (int)(rel * sc2); bin = bin > 255 ? 255 : bin;
          atomicAdd(&hist[512 + bin], 1);
        }
      }
    }
    if (!dn3) {
#pragma unroll
      for (int i = 0; i < 16; ++i) {
        const float rel = d23[i][1] - lo3;
        if (rel >= 0.0f && rel < R3) {
          int bin = (int)(rel * sc3); bin = bin > 255 ? 255 : bin;
          atomicAdd(&hist[768 + bin], 1);
        }
      }
    }
    __syncthreads();
    {   // wave w: prefix scan of query w's histogram
      const bool skip = wid == 0 ? dn0 : wid == 1 ? dn1 : wid == 2 ? dn2 : dn3;
      if (!skip) {
        const int* h = &hist[wid * 256];
        int s0 = h[lane], s1 = h[64 + lane], s2 = h[128 + lane], s3 = h[192 + lane];
#pragma unroll
        for (int off = 1; off < 64; off <<= 1) { const int t = __shfl_up(s0, off); if (lane >= off) s0 += t; }
#pragma unroll
        for (int off = 1; off < 64; off <<= 1) { const int t = __shfl_up(s1, off); if (lane >= off) s1 += t; }
#pragma unroll
        for (int off = 1; off < 64; off <<= 1) { const int t = __shfl_up(s2, off); if (lane >= off) s2 += t; }
#pragma unroll
        for (int off = 1; off < 64; off <<= 1) { const int t = __shfl_up(s3, off); if (lane >= off) s3 += t; }
        s1 += __shfl(s0, 63);
        s2 += __shfl(s1, 63);
        s3 += __shfl(s2, 63);
        const int bef = wid == 0 ? bef0 : wid == 1 ? bef1 : wid == 2 ? bef2 : bef3;
        s0 += bef; s1 += bef; s2 += bef; s3 += bef;
        int B = 256, cnt = 0;
        unsigned long long m = __ballot(s0 >= 20);
        if (m) { const int l = __ffsll((long long)m) - 1; B = l; cnt = __shfl(s0, l); }
        else if ((m = __ballot(s1 >= 20)) != 0ull) { const int l = __ffsll((long long)m) - 1; B = 64 + l; cnt = __shfl(s1, l); }
        else if ((m = __ballot(s2 >= 20)) != 0ull) { const int l = __ffsll((long long)m) - 1; B = 128 + l; cnt = __shfl(s2, l); }
        else if ((m = __ballot(s3 >= 20)) != 0ull) { const int l = __ffsll((long long)m) - 1; B = 192 + l; cnt = __shfl(s3, l); }
        if (lane == 0) { sB[wid * 2] = B; sB[wid * 2 + 1] = cnt; }
      }
    }
    __syncthreads();
    // block-uniform per-query decisions
    bool zm0 = false, zm1 = false, zm2 = false, zm3 = false;
    if (!dn0) {
      const int Bq = sB[0], cq = sB[1];
      if (Bq == 256) R0 *= 16.0f;
      else {
        const float bw = R0 * (1.0f / 256.0f);
        Dedge0 = lo0 + (float)(Bq + 1) * bw;
        if (cq <= 48) dn0 = true;
        else { lo0 += (float)Bq * bw; R0 = bw; zm0 = true; }
      }
    }
    if (!dn1) {
      const int Bq = sB[2], cq = sB[3];
      if (Bq == 256) R1 *= 16.0f;
      else {
        const float bw = R1 * (1.0f / 256.0f);
        Dedge1 = lo1 + (float)(Bq + 1) * bw;
        if (cq <= 48) dn1 = true;
        else { lo1 += (float)Bq * bw; R1 = bw; zm1 = true; }
      }
    }
    if (!dn2) {
      const int Bq = sB[4], cq = sB[5];
      if (Bq == 256) R2 *= 16.0f;
      else {
        const float bw = R2 * (1.0f / 256.0f);
        Dedge2 = lo2 + (float)(Bq + 1) * bw;
        if (cq <= 48) dn2 = true;
        else { lo2 += (float)Bq * bw; R2 = bw; zm2 = true; }
      }
    }
    if (!dn3) {
      const int Bq = sB[6], cq = sB[7];
      if (Bq == 256) R3 *= 16.0f;
      else {
        const float bw = R3 * (1.0f / 256.0f);
        Dedge3 = lo3 + (float)(Bq + 1) * bw;
        if (cq <= 48) dn3 = true;
        else { lo3 += (float)Bq * bw; R3 = bw; zm3 = true; }
      }
    }
    if (zm0) {
      int c = 0;
#pragma unroll
      for (int i = 0; i < 16; ++i) c += (int)__popcll(__ballot(d01[i][0] < lo0));
      if (lane == 0) wcnt[0][wid] = c;
    }
    if (zm1) {
      int c = 0;
#pragma unroll
      for (int i = 0; i < 16; ++i) c += (int)__popcll(__ballot(d01[i][1] < lo1));
      if (lane == 0) wcnt[1][wid] = c;
    }
    if (zm2) {
      int c = 0;
#pragma unroll
      for (int i = 0; i < 16; ++i) c += (int)__popcll(__ballot(d23[i][0] < lo2));
      if (lane == 0) wcnt[2][wid] = c;
    }
    if (zm3) {
      int c = 0;
#pragma unroll
      for (int i = 0; i < 16; ++i) c += (int)__popcll(__ballot(d23[i][1] < lo3));
      if (lane == 0) wcnt[3][wid] = c;
    }
    if (zm0 | zm1 | zm2 | zm3) {
      __syncthreads();
      if (zm0) bef0 = wcnt[0][0] + wcnt[0][1] + wcnt[0][2] + wcnt[0][3];
      if (zm1) bef1 = wcnt[1][0] + wcnt[1][1] + wcnt[1][2] + wcnt[1][3];
      if (zm2) bef2 = wcnt[2][0] + wcnt[2][1] + wcnt[2][2] + wcnt[2][3];
      if (zm3) bef3 = wcnt[3][0] + wcnt[3][1] + wcnt[3][2] + wcnt[3][3];
    }
  }

  // ---- margin collect (all four queries) ----
  if (tid < 4) scnt[tid] = 0;
  __syncthreads();
  const float T0 = Dedge0 + 4e-3f, T1 = Dedge1 + 4e-3f;
  const float T2 = Dedge2 + 4e-3f, T3 = Dedge3 + 4e-3f;
#pragma unroll
  for (int i = 0; i < 16; ++i) {
    if (d01[i][0] < T0) {
      const int pos = atomicAdd(&scnt[0], 1);
      if (pos < 64) slist[0][pos] = i * 256 + tid;
    }
    if (d01[i][1] < T1) {
      const int pos = atomicAdd(&scnt[1], 1);
      if (pos < 64) slist[1][pos] = i * 256 + tid;
    }
    if (d23[i][0] < T2) {
      const int pos = atomicAdd(&scnt[2], 1);
      if (pos < 64) slist[2][pos] = i * 256 + tid;
    }
    if (d23[i][1] < T3) {
      const int pos = atomicAdd(&scnt[3], 1);
      if (pos < 64) slist[3][pos] = i * 256 + tid;
    }
  }
  __syncthreads();

  // wave w: f64 re-rank of query w (reference op order -> exact top-20 set)
  const float4 cp = wid == 0 ? cp0 : wid == 1 ? cp1 : wid == 2 ? cp2 : cp3;
  {
    const int s = min(scnt[wid], 64);
    int myi = -1; double myd = -1.0e300;
    if (lane < s) {
      myi = slist[wid][lane];
      const float4 av = xb4[myi];
      const double c0 = (double)cp.x, c1 = (double)cp.y, c2 = (double)cp.z;
      const double a0 = (double)av.x, a1 = (double)av.y, a2 = (double)av.z;
      const double dot = c0 * a0 + c1 * a1 + c2 * a2;
      const double sqm = a0 * a0 + a1 * a1 + a2 * a2;
      const double sn  = c0 * c0 + c1 * c1 + c2 * c2;
      myd = (2.0 * dot - sn) - sqm;
    }
    int rank = 0;
    for (int j = 0; j < s; ++j) {
      const double od = __shfl(myd, j);
      const int    oi = __shfl(myi, j);
      if (od > myd || (od == myd && oi < myi)) ++rank;
    }
    if (lane < s && rank < KNN) {
      idx_out[(p0 + wid) * KNN + rank] = myi;
      eidx[wid][rank] = myi;
    }
  }
  // same-wave LDS write->read is in-order; no barrier needed before stats.

  // fused layer-1 stats: wave w handles query w, all 20 k, ch = lane
  const float base1 = (w1r[3] - w1r[0]) * cp.x + (w1r[4] - w1r[1]) * cp.y +
                      (w1r[5] - w1r[2]) * cp.z;
  float sm = 0.f, sq = 0.f;
#pragma unroll
  for (int t = 0; t < KNN; ++t) {
    const int kk = eidx[wid][t];
    const float4 qv = xb4[kk];                // same-addr broadcast
    float y = fmaf(w1r[0], qv.x, fmaf(w1r[1], qv.y, fmaf(w1r[2], qv.z, base1)));
    y = lrelu(y);
    sm += y; sq = fmaf(y, y, sq);
  }
  float* bk = s1buf + (size_t)((p0 + wid) & 255) * 128;
  atomicAdd(&bk[lane], sm);
  atomicAdd(&bk[64 + lane], sq);
}

// ---------------------------------------------------------------------------
// Stage kernel v2 (R10): one wave per point, 4 waves/block, 8 points/wave.
// R10 measurement: stage3 = 130us but issue cost ~25us -> >80% stall at
// 2 waves/SIMD. Fix: move the MFMA B-operand weight fragments (identical
// across waves) from VGPRs to LDS (8KB/layer), read just-in-time per MFMA
// pair (per-lane sequential 16B reads, conflict-free, wave-uniform base).
// Frees 64 VGPRs in stage3 (32 in stage2) -> live set ~110 regs -> raise
// occupancy: stage2 MINW 3->4, stage3 2->3 (budget 170 >> 110; R8's
// failure was register-resident weights at ~190 live vs 170 budget).
// Bitwise-identical math (same f2bf values, same MFMA operands).
// ---------------------------------------------------------------------------
template <int STAGE, int MINW>
__global__ __launch_bounds__(256, MINW) void stage_kernel(
    const float4* __restrict__ xt4, const int* __restrict__ nbr,
    const float* __restrict__ W1,
    const float* __restrict__ w2ft, const float* __restrict__ b2f,
    const float* __restrict__ w3ft, const float* __restrict__ b3f,
    float* __restrict__ sumO, float* __restrict__ sqO,
    float* __restrict__ mx, float* __restrict__ mn) {
  __shared__ float pts[4][96];          // float4 per k, center at 80..83
  __shared__ float W1T[384];
  __shared__ short abuf[4][2048];       // per-wave A-frag buffer
  __shared__ float redS[256], redQ[256];
  __shared__ short wl[STAGE == 3 ? 8192 : 4096];  // B-frags: [w][ktnt][lane][8]

  const int tid = threadIdx.x, wave = tid >> 6, lane = tid & 63;
  const int q = lane >> 4, cc = lane & 15;

  for (int i = tid; i < 384; i += 256) W1T[i] = W1[(i & 63) * 6 + (i >> 6)];
  // stage B-frag weights into LDS: slot s = {which, kt, nt, ln}; 8 bf16 each
  {
    const int nslot = (STAGE == 3) ? 1024 : 512;
    for (int s = tid; s < nslot; s += 256) {
      const int which = s >> 9;            // 0 = w2, 1 = w3
      const int slot = s & 511;
      const int ktnt = slot >> 6, ln = slot & 63;
      const int kt = ktnt >> 2, nt = ktnt & 3;
      const int qq = ln >> 4, ccq = ln & 15;
      const float* src = which ? w3ft : w2ft;
      short* dst = &wl[s * 8];
#pragma unroll
      for (int j = 0; j < 8; ++j)
        dst[j] = f2bf(src[(kt * 32 + qq * 8 + j) * 64 + nt * 16 + ccq]);
    }
  }
  __syncthreads();

  float w1r[6];
#pragma unroll
  for (int c = 0; c < 6; ++c) w1r[c] = W1T[c * 64 + lane];

  float bias2v[4];
#pragma unroll
  for (int nt = 0; nt < 4; ++nt) bias2v[nt] = b2f[nt * 16 + cc];
  float bias3v[4];
  if (STAGE == 3) {
#pragma unroll
    for (int nt = 0; nt < 4; ++nt) bias3v[nt] = b3f[nt * 16 + cc];
  }

  const bf16x8* w2v = (const bf16x8*)wl;              // [ktnt*64 + lane]
  const bf16x8* w3v = (const bf16x8*)&wl[4096];       // stage3 only

  const int kt1 = lane >> 5, q1 = (lane & 31) >> 3, j1 = lane & 7;
  short* ab = abuf[wave];
  const bf16x8* ab8 = (const bf16x8*)ab;
  float* pw = pts[wave];

  float s_s[4] = {0.f, 0.f, 0.f, 0.f}, s_q[4] = {0.f, 0.f, 0.f, 0.f};
  const int wgid = blockIdx.x * 4 + wave;

  // --- pipelined gather state ---
  const int stepN = 8192 * KNN;
  const int* nbp = nbr + (size_t)wgid * KNN + lane;      // valid for lane<KNN
  const float4* xb0 = xt4 + (size_t)(wgid >> 12) * 4096; // batch base, it=0
  const int nn = wgid & 4095;                            // it-invariant
  int kkB = 0;
  float4 g;
  if (lane < KNN) {
    const int kkA = nbp[0];
    g = xb0[kkA];
    kkB = nbp[stepN];                                    // idx for it=1
  } else if (lane == KNN) {
    g = xb0[nn];
  }
  const int* nbp2 = nbp + 2 * stepN;                     // idx ptr for it+2
  const float4* xbn = xb0 + 8192;                        // batch base, it+1

  for (int it = 0; it < 8; ++it) {
    const int p = wgid + it * 8192;
    if (lane <= KNN) *(float4*)&pw[lane * 4] = g;
    // prefetch next point's gather (kkB ready) and idx two ahead
    float4 gn = g; int kkC = kkB;
    if (it < 7 && lane <= KNN) gn = (lane < KNN) ? xbn[kkB] : xbn[nn];
    if (it < 6 && lane < KNN) kkC = nbp2[0];

    const float cx0 = pw[80], cx1 = pw[81], cx2 = pw[82];
    const float base1 = (w1r[3] - w1r[0]) * cx0 + (w1r[4] - w1r[1]) * cx1 +
                        (w1r[5] - w1r[2]) * cx2;

#pragma unroll
    for (int k = 0; k < KNN; ++k) {
      const float4 pk = *(const float4*)&pw[k * 4];
      float y = fmaf(w1r[0], pk.x, fmaf(w1r[1], pk.y, fmaf(w1r[2], pk.z, base1)));
      y = lrelu(y);
      ab[(((k >> 4) * 2 + kt1) * 64 + q1 * 16 + (k & 15)) * 8 + j1] = f2bf(y);
    }

    f32x4 acc2[2][4];
#pragma unroll
    for (int mt = 0; mt < 2; ++mt)
#pragma unroll
      for (int nt = 0; nt < 4; ++nt)
        acc2[mt][nt] = f32x4{bias2v[nt], bias2v[nt], bias2v[nt], bias2v[nt]};
#pragma unroll
    for (int kt = 0; kt < 2; ++kt) {
      const bf16x8 a0 = ab8[(0 * 2 + kt) * 64 + lane];
      const bf16x8 a1 = ab8[(1 * 2 + kt) * 64 + lane];
#pragma unroll
      for (int nt = 0; nt < 4; ++nt) {
        const bf16x8 bw = w2v[(kt * 4 + nt) * 64 + lane];
        acc2[0][nt] = __builtin_amdgcn_mfma_f32_16x16x32_bf16(a0, bw, acc2[0][nt], 0, 0, 0);
        acc2[1][nt] = __builtin_amdgcn_mfma_f32_16x16x32_bf16(a1, bw, acc2[1][nt], 0, 0, 0);
      }
    }

    if (STAGE == 2) {
#pragma unroll
      for (int mt = 0; mt < 2; ++mt)
#pragma unroll
        for (int nt = 0; nt < 4; ++nt)
#pragma unroll
          for (int r = 0; r < 4; ++r) {
            if (mt == 1 && q != 0) continue;
            const float y = lrelu(acc2[mt][nt][r]);
            s_s[nt] += y; s_q[nt] += y * y;
          }
    } else {
#pragma unroll
      for (int mt = 0; mt < 2; ++mt)
#pragma unroll
        for (int nt = 0; nt < 4; ++nt) {
          const int kt3 = nt >> 1;
          const int q3 = (nt & 1) * 2 + (cc >> 3);
          const int j3 = cc & 7;
#pragma unroll
          for (int r = 0; r < 4; ++r) {
            if (mt == 1 && q != 0) continue;
            const float y = lrelu(acc2[mt][nt][r]);
            ab[((mt * 2 + kt3) * 64 + q3 * 16 + q * 4 + r) * 8 + j3] = f2bf(y);
          }
        }

      f32x4 acc3[2][4];
#pragma unroll
      for (int mt = 0; mt < 2; ++mt)
#pragma unroll
        for (int nt = 0; nt < 4; ++nt)
          acc3[mt][nt] = f32x4{bias3v[nt], bias3v[nt], bias3v[nt], bias3v[nt]};
#pragma unroll
      for (int kt = 0; kt < 2; ++kt) {
        const bf16x8 a0 = ab8[(0 * 2 + kt) * 64 + lane];
        const bf16x8 a1 = ab8[(1 * 2 + kt) * 64 + lane];
#pragma unroll
        for (int nt = 0; nt < 4; ++nt) {
          const bf16x8 bw = w3v[(kt * 4 + nt) * 64 + lane];
          acc3[0][nt] = __builtin_amdgcn_mfma_f32_16x16x32_bf16(a0, bw, acc3[0][nt], 0, 0, 0);
          acc3[1][nt] = __builtin_amdgcn_mfma_f32_16x16x32_bf16(a1, bw, acc3[1][nt], 0, 0, 0);
        }
      }

      float vmx[4], vmn[4];
#pragma unroll
      for (int nt = 0; nt < 4; ++nt) { vmx[nt] = -INFINITY; vmn[nt] = INFINITY; }
#pragma unroll
      for (int mt = 0; mt < 2; ++mt)
#pragma unroll
        for (int nt = 0; nt < 4; ++nt)
#pragma unroll
          for (int r = 0; r < 4; ++r) {
            if (mt == 1 && q != 0) continue;
            const float y = lrelu(acc3[mt][nt][r]);
            s_s[nt] += y; s_q[nt] += y * y;
            vmx[nt] = fmaxf(vmx[nt], y); vmn[nt] = fminf(vmn[nt], y);
          }
#pragma unroll
      for (int nt = 0; nt < 4; ++nt) {
        vmx[nt] = fmaxf(vmx[nt], __shfl_xor(vmx[nt], 16));
        vmx[nt] = fmaxf(vmx[nt], __shfl_xor(vmx[nt], 32));
        vmn[nt] = fminf(vmn[nt], __shfl_xor(vmn[nt], 16));
        vmn[nt] = fminf(vmn[nt], __shfl_xor(vmn[nt], 32));
      }
      const float omx = q == 0 ? vmx[0] : q == 1 ? vmx[1] : q == 2 ? vmx[2] : vmx[3];
      const float omn = q == 0 ? vmn[0] : q == 1 ? vmn[1] : q == 2 ? vmn[2] : vmn[3];
      mx[(size_t)p * 64 + lane] = omx;
      mn[(size_t)p * 64 + lane] = omn;
    }

    g = gn; kkB = kkC; nbp2 += stepN; xbn += 8192;
  }

#pragma unroll
  for (int nt = 0; nt < 4; ++nt) {
    s_s[nt] += __shfl_xor(s_s[nt], 16); s_s[nt] += __shfl_xor(s_s[nt], 32);
    s_q[nt] += __shfl_xor(s_q[nt], 16); s_q[nt] += __shfl_xor(s_q[nt], 32);
  }
  const float ms = q == 0 ? s_s[0] : q == 1 ? s_s[1] : q == 2 ? s_s[2] : s_s[3];
  const float mq = q == 0 ? s_q[0] : q == 1 ? s_q[1] : q == 2 ? s_q[2] : s_q[3];
  redS[tid] = ms; redQ[tid] = mq;
  __syncthreads();
  if (tid < 64) {
    const float s  = redS[tid] + redS[64 + tid] + redS[128 + tid] + redS[192 + tid];
    const float qq = redQ[tid] + redQ[64 + tid] + redQ[128 + tid] + redQ[192 + tid];
    atomicAdd(&sumO[tid], s);
    atomicAdd(&sqO[tid], qq);
  }
}

// fold1 v2 (R6): 256 threads — thread (o=tid&63, qt=tid>>6) sums bucket
// quarter qt, LDS-reduce, then quarter-split W-fold. Same math, 4x parallel.
__global__ __launch_bounds__(256) void fold1_kernel(
    const float* __restrict__ s1buf,
    const float* __restrict__ g, const float* __restrict__ bt,
    const float* __restrict__ W,
    float* __restrict__ WfT, float* __restrict__ bf) {
  __shared__ float rs[256], rq[256];
  __shared__ float s[64], t[64];
  const int tid = threadIdx.x, o = tid & 63, qt = tid >> 6;
  float sm = 0.f, qq = 0.f;
  for (int k = qt; k < 256; k += 4) {
    sm += s1buf[k * 128 + o];
    qq += s1buf[k * 128 + 64 + o];
  }
  rs[tid] = sm; rq[tid] = qq;
  __syncthreads();
  if (tid < 64) {
    sm = rs[o] + rs[64 + o] + rs[128 + o] + rs[192 + o];
    qq = rq[o] + rq[64 + o] + rq[128 + o] + rq[192 + o];
    const float mu = sm * CNT_INV;
    const float var = qq * CNT_INV - mu * mu;
    const float sc = g[o] / sqrtf(var + 1e-5f);
    s[o] = sc; t[o] = bt[o] - mu * sc;
  }
  __syncthreads();
  float acc = 0.f;
  for (int c = qt * 16; c < qt * 16 + 16; ++c) {
    const float w = W[o * 64 + c];
    WfT[c * 64 + o] = w * s[c];
    acc = fmaf(w, t[c], acc);
  }
  rs[tid] = acc;
  __syncthreads();
  if (tid < 64) bf[o] = rs[o] + rs[64 + o] + rs[128 + o] + rs[192 + o];
}

__global__ void fold_kernel(const float* __restrict__ sum, const float* __restrict__ sq,
                            const float* __restrict__ g, const float* __restrict__ bt,
                            const float* __restrict__ W,
                            float* __restrict__ WfT, float* __restrict__ bf) {
  __shared__ float s[64], t[64];
  const int o = threadIdx.x;
  const float mu = sum[o] * CNT_INV;
  const float var = sq[o] * CNT_INV - mu * mu;
  const float sc = g[o] / sqrtf(var + 1e-5f);
  s[o] = sc; t[o] = bt[o] - mu * sc;
  __syncthreads();
  float acc = 0.f;
  for (int c = 0; c < 64; ++c) {
    const float w = W[o * 64 + c];
    WfT[c * 64 + o] = w * s[c];
    acc += w * t[c];
  }
  bf[o] = acc;
}

// final (R6): fold3 fused — each block derives s3/t3 from BN3 raw stats.
// 64x64 LDS transpose tile; coalesced reads of mx/mn AND writes of out.
// out[b][o][n] = s3[o] * (s3>=0 ? max_k : min_k) + t3[o]
__global__ __launch_bounds__(256) void final_kernel(
    const float* __restrict__ mx, const float* __restrict__ mn,
    const float* __restrict__ sum3, const float* __restrict__ sq3,
    const float* __restrict__ g2, const float* __restrict__ b2,
    float* __restrict__ out) {
  __shared__ float tmx[64][65], tmn[64][65];
  __shared__ float ss[64], tt[64];
  const int tid = threadIdx.x;
  const int P = blockIdx.x * 64;              // 64 points, same batch b
  const int b = P >> 12, nb = P & 4095;
  if (tid < 64) {
    const float mu = sum3[tid] * CNT_INV;
    const float var = sq3[tid] * CNT_INV - mu * mu;
    const float sc = g2[tid] / sqrtf(var + 1e-5f);
    ss[tid] = sc; tt[tid] = b2[tid] - mu * sc;
  }
#pragma unroll
  for (int r = 0; r < 16; ++r) {
    const int idx = r * 256 + tid;            // point-local row, channel
    const int pl = idx >> 6, ch = idx & 63;
    const size_t src = ((size_t)(P + pl)) * 64 + ch;
    tmx[pl][ch] = mx[src];
    tmn[pl][ch] = mn[src];
  }
  __syncthreads();
  const int nl = tid & 63;
#pragma unroll
  for (int r = 0; r < 16; ++r) {
    const int o = (tid >> 6) + r * 4;
    const float sc = ss[o];
    const float v = sc >= 0.f ? tmx[nl][o] : tmn[nl][o];
    out[(size_t)b * 262144 + (size_t)o * 4096 + nb + nl] = sc * v + tt[o];
  }
}

extern "C" void kernel_launch(void* const* d_in, const int* in_sizes, int n_in,
                              void* d_out, int out_size, void* d_ws, size_t ws_size,
                              hipStream_t stream) {
  const float* x  = (const float*)d_in[0];
  const float* W1 = (const float*)d_in[1];
  const float* W2 = (const float*)d_in[2];
  const float* W3 = (const float*)d_in[3];
  const float* g1 = (const float*)d_in[4];
  const float* b1 = (const float*)d_in[5];
  const float* g2 = (const float*)d_in[6];
  const float* b2 = (const float*)d_in[7];
  float* out = (float*)d_out;

  char* ws = (char*)d_ws;
  float4* xt4 = (float4*)ws;                        // 1,048,576 B
  int* idx = (int*)(ws + 1048576);                  // 5,242,880 B
  float* F = (float*)(ws + 6291456);
  float* sum2 = F + 0,   * sq2 = F + 64;
  float* sum3 = F + 128, * sq3 = F + 192;
  float* s1buf = F + 256;                           // 256 buckets x 128
  float* W2fT = F + 33024;
  float* b2f  = F + 37120;
  float* W3fT = F + 37184;
  float* b3f  = F + 41280;
  float* mx = (float*)(ws + 6457344);               // [B*N][64]
  float* mn = mx + (size_t)16 * 4096 * 64;

  hipMemsetAsync(F, 0, 33024 * sizeof(float), stream);   // stats + buckets

  xt4_kernel<<<256, 256, 0, stream>>>(x, xt4);
  knn_kernel<<<16384, 256, 0, stream>>>(xt4, idx, W1, s1buf);
  fold1_kernel<<<1, 256, 0, stream>>>(s1buf, g1, b1, W2, W2fT, b2f);
  stage_kernel<2, 4><<<2048, 256, 0, stream>>>(xt4, idx, W1, W2fT, b2f, nullptr,
                                               nullptr, sum2, sq2, nullptr, nullptr);
  fold_kernel<<<1, 64, 0, stream>>>(sum2, sq2, g1, b1, W3, W3fT, b3f);
  stage_kernel<3, 3><<<2048, 256, 0, stream>>>(xt4, idx, W1, W2fT, b2f, W3fT,
                                               b3f, sum3, sq3, mx, mn);
  final_kernel<<<1024, 256, 0, stream>>>(mx, mn, sum3, sq3, g2, b2, out);
}